// Round 12
// baseline (193.781 us; speedup 1.0000x reference)
//
#include <hip/hip_runtime.h>
#include <hip/hip_bf16.h>

#define DEVFN __device__ __forceinline__

typedef __bf16 bf16x8 __attribute__((ext_vector_type(8)));
typedef float f32x4 __attribute__((ext_vector_type(4)));
typedef float float4_t __attribute__((ext_vector_type(4)));
typedef unsigned short ushort8_t __attribute__((ext_vector_type(8)));
typedef unsigned short ushort4_t __attribute__((ext_vector_type(4)));
typedef unsigned int uint4_t __attribute__((ext_vector_type(4)));

constexpr int Bd = 8, Cd = 512, Nd = 4096, Dd = 64;

DEVFN unsigned short f2bf(float f) {
    union { float f; unsigned int u; } v; v.f = f;
    unsigned int r = (v.u + 0x7FFFu + ((v.u >> 16) & 1u)) >> 16;
    return (unsigned short)r;
}

DEVFN unsigned int pack2(float a, float b) {   // two f32 -> packed bf16x2 (RNE)
    __hip_bfloat162 h = __float22bfloat162_rn(make_float2(a, b));
    union { __hip_bfloat162 h; unsigned int u; } c; c.h = h;
    return c.u;
}

DEVFN bf16x8 ld_bf8(const unsigned short* p) {
    ushort8_t u = *(const ushort8_t*)p;
    return __builtin_bit_cast(bf16x8, u);
}

DEVFN f32x4 mfma16(bf16x8 a, bf16x8 b, f32x4 c) {
    return __builtin_amdgcn_mfma_f32_16x16x32_bf16(a, b, c, 0, 0, 0);
}

// ---------------- K0: convert weights to bf16 ----------------
__global__ __launch_bounds__(256) void k_cvtw(
    const float* __restrict__ Wq, const float* __restrict__ Wk,
    const float* __restrict__ Wv, const float* __restrict__ Wo,
    unsigned short* __restrict__ w4)
{
    int i = blockIdx.x * 256 + threadIdx.x;   // 0..32767
    w4[i]          = f2bf(Wq[i]);
    w4[32768 + i]  = f2bf(Wk[i]);
    w4[65536 + i]  = f2bf(Wv[i]);
    w4[98304 + i]  = f2bf(Wo[i]);
}

// ---------------- K1 v7: QKV, 2 waves split C, zero inner barriers ----------------
// Block = 128 thr: wave w owns c in [w*256, w*256+256) (4 tiles of 64c) for the
// same 16 n-rows; wave-private LDS staging + 2-deep named-reg pipeline, NO
// barrier in the loop (round-10/11 validated). One final barrier: wave1 puts
// its 12 partial accs in LDS, wave0 adds and runs the validated epilogues.
// Grid 256x8 = 2048 blocks = 4096 waves -> 4 waves/SIMD (2x round-11 MLP).
__global__ __launch_bounds__(128, 4) void k_qkv(
    const float* __restrict__ x,
    const unsigned short* __restrict__ w4,
    const float* __restrict__ bq, const float* __restrict__ bk, const float* __restrict__ bv,
    unsigned short* __restrict__ q_nd, unsigned short* __restrict__ k_nd,
    unsigned short* __restrict__ v_dn)
{
    const int n0w = blockIdx.x * 16;
    const int b   = blockIdx.y;
    const int tid = threadIdx.x;
    const int w   = tid >> 6;                    // C-half
    const int l   = tid & 63, lo = l & 15, hi = l >> 4;
    const int cb  = w * 256;
    const float* xb = x + (size_t)b * Cd * Nd + n0w;

    __shared__ __align__(16) unsigned short stg[2][16 * 72]; // per-wave x-staging
    __shared__ __align__(16) float red[12][64][4];           // wave1 partials (12 KB)
    __shared__ __align__(16) unsigned short epi[64 * 24];    // epilogue scratch (wave0)

    unsigned short* sm = &stg[w][0];

    f32x4 acc[12] = {};
    float4_t xsA[4], xsB[4];

    auto gloadA = [&](int t) {
        const float* p = xb + (size_t)(cb + t * 64 + l) * Nd;
        #pragma unroll
        for (int i = 0; i < 4; ++i) xsA[i] = *(const float4_t*)(p + i * 4);
    };
    auto gloadB = [&](int t) {
        const float* p = xb + (size_t)(cb + t * 64 + l) * Nd;
        #pragma unroll
        for (int i = 0; i < 4; ++i) xsB[i] = *(const float4_t*)(p + i * 4);
    };
    auto dswriteA = [&]() {     // transpose: sm[n-local i][c-local l]
        #pragma unroll
        for (int i = 0; i < 16; ++i)
            sm[i * 72 + l] = f2bf(xsA[i >> 2][i & 3]);
    };
    auto dswriteB = [&]() {
        #pragma unroll
        for (int i = 0; i < 16; ++i)
            sm[i * 72 + l] = f2bf(xsB[i >> 2][i & 3]);
    };
    auto compute = [&](int t) {
        #pragma unroll
        for (int kk = 0; kk < 2; ++kk) {
            bf16x8 af = ld_bf8(&sm[lo * 72 + kk * 32 + hi * 8]);
            #pragma unroll
            for (int j = 0; j < 12; ++j) {
                const unsigned short* wm = w4 + (j >> 2) * 32768;
                bf16x8 bf = ld_bf8(wm + ((j & 3) * 16 + lo) * Cd + cb + t * 64 + kk * 32 + hi * 8);
                acc[j] = mfma16(af, bf, acc[j]);
            }
        }
    };

    gloadA(0);
    gloadB(1);
    for (int t = 0; t < 4; t += 2) {
        dswriteA();                              // tile t (waits only its own regs)
        asm volatile("" ::: "memory");
        if (t + 2 < 4) gloadA(t + 2);
        __builtin_amdgcn_sched_barrier(0);       // pin loads (validated pattern)
        compute(t);
        asm volatile("" ::: "memory");           // reads before overwrite (in-order DS)
        dswriteB();                              // tile t+1
        asm volatile("" ::: "memory");
        if (t + 3 < 4) gloadB(t + 3);
        __builtin_amdgcn_sched_barrier(0);
        compute(t + 1);
        asm volatile("" ::: "memory");
    }

    // ---- cross-wave reduce (single barrier in kernel) ----
    if (w == 1) {
        #pragma unroll
        for (int j = 0; j < 12; ++j)
            *(f32x4*)&red[j][l][0] = acc[j];
    }
    __syncthreads();
    if (w == 1) return;

    #pragma unroll
    for (int j = 0; j < 12; ++j)
        acc[j] += *(const f32x4*)&red[j][l][0];

    // ---- epilogue: q, k via per-wave LDS transpose (validated v6 pattern) ----
    #pragma unroll
    for (int m = 0; m < 2; ++m) {
        const float* bias = m ? bk : bq;
        #pragma unroll
        for (int j = 0; j < 4; ++j) {
            const float bia = bias[j * 16 + lo];
            #pragma unroll
            for (int r = 0; r < 4; ++r)
                epi[(hi * 4 + r) * 72 + j * 16 + lo] = f2bf(acc[m * 4 + j][r] + bia);
        }
        asm volatile("" ::: "memory");
        const int row = l >> 2, dg = l & 3;
        ushort8_t a0 = *(const ushort8_t*)&epi[row * 72 + dg * 16];
        ushort8_t a1 = *(const ushort8_t*)&epi[row * 72 + dg * 16 + 8];
        unsigned short* dst = (m ? k_nd : q_nd)
            + ((size_t)b * Nd + n0w + row) * 64 + dg * 16;
        *(ushort8_t*)dst = a0; *(ushort8_t*)(dst + 8) = a1;
        asm volatile("" ::: "memory");           // m=0 reads before m=1 overwrites
    }

    // ---- epilogue: v via [64d][24] transpose, 32B d-row stores ----
    #pragma unroll
    for (int j = 0; j < 4; ++j) {
        const float bia = bv[j * 16 + lo];
        #pragma unroll
        for (int r = 0; r < 4; ++r)
            epi[(j * 16 + lo) * 24 + hi * 4 + r] = f2bf(acc[8 + j][r] + bia);
    }
    asm volatile("" ::: "memory");
    {
        ushort8_t a0 = *(const ushort8_t*)&epi[l * 24];
        ushort8_t a1 = *(const ushort8_t*)&epi[l * 24 + 8];
        unsigned short* dst = v_dn + ((size_t)b * Dd + l) * Nd + n0w;
        *(ushort8_t*)dst = a0; *(ushort8_t*)(dst + 8) = a1;
    }
}

// ---------------- K2: flash attention, 2qh x 2kh wave split (round-6/9 validated, 62.7us) ----
__global__ __launch_bounds__(256, 2) void k_attn(
    const unsigned short* __restrict__ q_nd,
    const unsigned short* __restrict__ k_nd,
    const unsigned short* __restrict__ v_dn,
    unsigned short* __restrict__ o_nd)
{
    const int bid = blockIdx.x;
    const int b   = bid & 7;            // round-robin XCD dispatch -> batch-per-XCD L2 locality
    const int n0  = (bid >> 3) * 64;
    const int tid = threadIdx.x, wid = tid >> 6, l = tid & 63;
    const int lo  = l & 15, hi = l >> 4;
    const int lsw = lo & 7;
    const int qh  = wid >> 1;           // q-half (32 rows)
    const int kh  = wid & 1;            // key-half (32 keys)
    const int wk0 = kh * 32;

    __shared__ unsigned short k_tiles[2][64 * 64];
    __shared__ unsigned short v_tiles[2][64 * 64];
    __shared__ float red_acc[2][2][4][256];   // [qh][qs][ds][lane*4]
    __shared__ float red_l[2][2][16];         // [qh][qs][lo]

    const unsigned short* qb = q_nd + (size_t)b * Nd * Dd;
    const unsigned short* kb = k_nd + (size_t)b * Nd * Dd;
    const unsigned short* vb = v_dn + (size_t)b * Dd * Nd;

    bf16x8 aq[2][2];
    #pragma unroll
    for (int qs = 0; qs < 2; ++qs)
        #pragma unroll
        for (int kc = 0; kc < 2; ++kc)
            aq[qs][kc] = ld_bf8(qb + (size_t)(n0 + qh*32 + qs*16 + lo) * 64 + kc*32 + hi*8);

    f32x4 acc[2][4] = {};
    float l_p[2] = {0.f, 0.f};

    const int sr = tid >> 3, ss = tid & 7;
    const int kwsl = (ss ^ (sr & 7)) * 8;
    const int vkh = ss >> 2, vsl = ss & 3, vms = vsl >> 1;
    const int vg0 = vkh * 4 + ((2 * vsl) & 3);
    const int vg1 = vkh * 4 + ((2 * vsl + 1) & 3);
    const int vsw = sr & 7;
    ushort8_t kr0, kr1, vr0, vr1;

    auto gload = [&](int t) {
        const size_t m1 = (size_t)t * 64;
        kr0 = *(const ushort8_t*)(kb + (m1 + sr) * 64 + ss * 8);
        kr1 = *(const ushort8_t*)(kb + (m1 + 32 + sr) * 64 + ss * 8);
        vr0 = *(const ushort8_t*)(vb + (size_t)sr * Nd + m1 + ss * 8);
        vr1 = *(const ushort8_t*)(vb + (size_t)(32 + sr) * Nd + m1 + ss * 8);
    };
    auto dswrite = [&](int buf) {
        unsigned short* kt = k_tiles[buf];
        unsigned short* vt = v_tiles[buf];
        *(ushort8_t*)(kt + sr * 64 + kwsl)        = kr0;
        *(ushort8_t*)(kt + (32 + sr) * 64 + kwsl) = kr1;
        ushort4_t a0 = __builtin_shufflevector(vr0, vr0, 0, 1, 2, 3);
        ushort4_t a1 = __builtin_shufflevector(vr0, vr0, 4, 5, 6, 7);
        ushort4_t b0 = __builtin_shufflevector(vr1, vr1, 0, 1, 2, 3);
        ushort4_t b1 = __builtin_shufflevector(vr1, vr1, 4, 5, 6, 7);
        *(ushort4_t*)(vt + sr * 64 + (vg0 ^ vsw) * 8 + vms * 4)        = a0;
        *(ushort4_t*)(vt + sr * 64 + (vg1 ^ vsw) * 8 + vms * 4)        = a1;
        *(ushort4_t*)(vt + (32 + sr) * 64 + (vg0 ^ vsw) * 8 + vms * 4) = b0;
        *(ushort4_t*)(vt + (32 + sr) * 64 + (vg1 ^ vsw) * 8 + vms * 4) = b1;
    };

    auto compute = [&](int buf) {
        const unsigned short* kt = k_tiles[buf];
        const unsigned short* vt = v_tiles[buf];
        f32x4 s[2][2] = {};
        #pragma unroll
        for (int ms = 0; ms < 2; ++ms) {
            #pragma unroll
            for (int kc = 0; kc < 2; ++kc) {
                bf16x8 kf = ld_bf8(kt + (wk0 + ms*16 + lo) * 64 + (((kc*4 + hi) ^ lsw) * 8));
                #pragma unroll
                for (int qs = 0; qs < 2; ++qs)
                    s[qs][ms] = mfma16(kf, aq[qs][kc], s[qs][ms]);
            }
        }
        bf16x8 vf[4];
        #pragma unroll
        for (int ds = 0; ds < 4; ++ds)
            vf[ds] = ld_bf8(vt + (ds*16 + lo) * 64 + (((kh*4 + hi) ^ lsw) * 8));
        #pragma unroll
        for (int qs = 0; qs < 2; ++qs) {
            float p[2][4];
            #pragma unroll
            for (int ms = 0; ms < 2; ++ms)
                #pragma unroll
                for (int r = 0; r < 4; ++r)
                    p[ms][r] = __expf(s[qs][ms][r]);
            l_p[qs] += ((p[0][0] + p[0][1]) + (p[0][2] + p[0][3]))
                     + ((p[1][0] + p[1][1]) + (p[1][2] + p[1][3]));
            uint4_t w;
            w[0] = pack2(p[0][0], p[0][1]);
            w[1] = pack2(p[0][2], p[0][3]);
            w[2] = pack2(p[1][0], p[1][1]);
            w[3] = pack2(p[1][2], p[1][3]);
            bf16x8 apf = __builtin_bit_cast(bf16x8, w);
            #pragma unroll
            for (int ds = 0; ds < 4; ++ds)
                acc[qs][ds] = mfma16(apf, vf[ds], acc[qs][ds]);
        }
    };

    constexpr int NT = Nd / 64;
    gload(0);
    dswrite(0);
    __syncthreads();
    for (int t = 0; t < NT; ++t) {
        const int cur = t & 1;
        if (t + 1 < NT) gload(t + 1);
        __builtin_amdgcn_sched_barrier(0);
        compute(cur);
        if (t + 1 < NT) dswrite(cur ^ 1);
        __syncthreads();
    }

    float lh[2];
    #pragma unroll
    for (int qs = 0; qs < 2; ++qs) {
        float ps = l_p[qs];
        ps += __shfl_xor(ps, 16, 64);
        ps += __shfl_xor(ps, 32, 64);
        lh[qs] = ps;
    }
    if (kh == 1) {
        #pragma unroll
        for (int qs = 0; qs < 2; ++qs) {
            #pragma unroll
            for (int ds = 0; ds < 4; ++ds)
                *(f32x4*)&red_acc[qh][qs][ds][l * 4] = acc[qs][ds];
            red_l[qh][qs][lo] = lh[qs];
        }
    }
    __syncthreads();
    if (kh == 0) {
        #pragma unroll
        for (int qs = 0; qs < 2; ++qs) {
            #pragma unroll
            for (int ds = 0; ds < 4; ++ds)
                acc[qs][ds] += *(const f32x4*)&red_acc[qh][qs][ds][l * 4];
            float l_tot = lh[qs] + red_l[qh][qs][lo];
            #pragma unroll
            for (int r = 0; r < 4; ++r) {
                float lq = __shfl(l_tot, hi * 4 + r, 16);
                float rl = 1.0f / lq;
                #pragma unroll
                for (int ds = 0; ds < 4; ++ds) {
                    float o = acc[qs][ds][r] * rl;
                    o_nd[((size_t)b * Nd + n0 + qh*32 + qs*16 + hi*4 + r) * 64 + ds*16 + lo] = f2bf(o);
                }
            }
        }
    }
}

// ---------------- K3: output projection + residual ----------------
__global__ __launch_bounds__(256) void k_oproj(
    const unsigned short* __restrict__ o_nd,
    const unsigned short* __restrict__ wo,
    const float* __restrict__ bo,
    const float* __restrict__ gamma,
    const float* __restrict__ x,
    float* __restrict__ out)
{
    const int b   = blockIdx.y;
    const int n0  = blockIdx.x * 64;
    const int tid = threadIdx.x, wid = tid >> 6, l = tid & 63;
    const int lo  = l & 15, hi = l >> 4;
    const int n0w = n0 + wid * 16;
    const float g = gamma[0];

    bf16x8 ao[2];
    #pragma unroll
    for (int kc = 0; kc < 2; ++kc)
        ao[kc] = ld_bf8(o_nd + ((size_t)b * Nd + n0w + lo) * 64 + kc*32 + hi*8);

    for (int ct = 0; ct < 32; ++ct) {
        f32x4 acc = {};
        #pragma unroll
        for (int kc = 0; kc < 2; ++kc) {
            bf16x8 bw = ld_bf8(wo + (ct*16 + lo) * 64 + kc*32 + hi*8);
            acc = mfma16(ao[kc], bw, acc);
        }
        const int c = ct*16 + lo;
        const float bc = bo[c];
        const size_t base = ((size_t)b * Cd + c) * Nd + n0w + hi*4;
        float4_t xv = *(const float4_t*)(x + base);
        float4_t ov;
        #pragma unroll
        for (int r = 0; r < 4; ++r) ov[r] = g * (acc[r] + bc) + xv[r];
        *(float4_t*)(out + base) = ov;
    }
}

extern "C" void kernel_launch(void* const* d_in, const int* in_sizes, int n_in,
                              void* d_out, int out_size, void* d_ws, size_t ws_size,
                              hipStream_t stream) {
    (void)in_sizes; (void)n_in; (void)out_size; (void)ws_size;
    const float* x  = (const float*)d_in[0];
    const float* Wq = (const float*)d_in[1];
    const float* bq = (const float*)d_in[2];
    const float* Wk = (const float*)d_in[3];
    const float* bk = (const float*)d_in[4];
    const float* Wv = (const float*)d_in[5];
    const float* bv = (const float*)d_in[6];
    const float* Wo = (const float*)d_in[7];
    const float* bo = (const float*)d_in[8];
    const float* gm = (const float*)d_in[9];
    float* out = (float*)d_out;

    unsigned short* w4   = (unsigned short*)d_ws;          // 4 x 32768 bf16 weights
    unsigned short* q_nd = w4 + 131072;
    unsigned short* k_nd = q_nd + (size_t)Bd * Nd * Dd;
    unsigned short* v_dn = k_nd + (size_t)Bd * Nd * Dd;
    unsigned short* o_nd = v_dn + (size_t)Bd * Nd * Dd;

    k_cvtw<<<128, 256, 0, stream>>>(Wq, Wk, Wv, Wo, w4);
    dim3 gq(Nd / 16, Bd);
    k_qkv<<<gq, 128, 0, stream>>>(x, w4, bq, bk, bv, q_nd, k_nd, v_dn);
    k_attn<<<512, 256, 0, stream>>>(q_nd, k_nd, v_dn, o_nd);
    dim3 g1(Nd / 64, Bd);
    k_oproj<<<g1, 256, 0, stream>>>(o_nd, w4 + 98304, bo, gm, x, out);
}

// Round 13
// 156.249 us; speedup vs baseline: 1.2402x; 1.2402x over previous
//
#include <hip/hip_runtime.h>
#include <hip/hip_bf16.h>

#define DEVFN __device__ __forceinline__

typedef __bf16 bf16x8 __attribute__((ext_vector_type(8)));
typedef float f32x4 __attribute__((ext_vector_type(4)));
typedef float float4_t __attribute__((ext_vector_type(4)));
typedef unsigned short ushort8_t __attribute__((ext_vector_type(8)));
typedef unsigned short ushort4_t __attribute__((ext_vector_type(4)));
typedef unsigned int uint4_t __attribute__((ext_vector_type(4)));

constexpr int Bd = 8, Cd = 512, Nd = 4096, Dd = 64;

DEVFN unsigned short f2bf(float f) {
    union { float f; unsigned int u; } v; v.f = f;
    unsigned int r = (v.u + 0x7FFFu + ((v.u >> 16) & 1u)) >> 16;
    return (unsigned short)r;
}

DEVFN unsigned int pack2(float a, float b) {   // two f32 -> packed bf16x2 (RNE)
    __hip_bfloat162 h = __float22bfloat162_rn(make_float2(a, b));
    union { __hip_bfloat162 h; unsigned int u; } c; c.h = h;
    return c.u;
}

DEVFN bf16x8 ld_bf8(const unsigned short* p) {
    ushort8_t u = *(const ushort8_t*)p;
    return __builtin_bit_cast(bf16x8, u);
}

DEVFN f32x4 mfma16(bf16x8 a, bf16x8 b, f32x4 c) {
    return __builtin_amdgcn_mfma_f32_16x16x32_bf16(a, b, c, 0, 0, 0);
}

// ---------------- K0: convert weights to bf16 ----------------
__global__ __launch_bounds__(256) void k_cvtw(
    const float* __restrict__ Wq, const float* __restrict__ Wk,
    const float* __restrict__ Wv, const float* __restrict__ Wo,
    unsigned short* __restrict__ w4)
{
    int i = blockIdx.x * 256 + threadIdx.x;   // 0..32767
    w4[i]          = f2bf(Wq[i]);
    w4[32768 + i]  = f2bf(Wk[i]);
    w4[65536 + i]  = f2bf(Wv[i]);
    w4[98304 + i]  = f2bf(Wo[i]);
}

// ---------------- K1 v7b: QKV, 2 waves split C, zero inner barriers, NO SPILL ----
// Round-12 regression root cause: __launch_bounds__(128,4) capped VGPR at 64
// while live state is ~100 -> scratch spills (97 MB writes). (128,2) caps at
// 256 -> allocator fits the live set; occupancy still ~4 waves/SIMD.
__global__ __launch_bounds__(128, 2) void k_qkv(
    const float* __restrict__ x,
    const unsigned short* __restrict__ w4,
    const float* __restrict__ bq, const float* __restrict__ bk, const float* __restrict__ bv,
    unsigned short* __restrict__ q_nd, unsigned short* __restrict__ k_nd,
    unsigned short* __restrict__ v_dn)
{
    const int n0w = blockIdx.x * 16;
    const int b   = blockIdx.y;
    const int tid = threadIdx.x;
    const int w   = tid >> 6;                    // C-half
    const int l   = tid & 63, lo = l & 15, hi = l >> 4;
    const int cb  = w * 256;
    const float* xb = x + (size_t)b * Cd * Nd + n0w;

    __shared__ __align__(16) unsigned short stg[2][16 * 72]; // per-wave x-staging
    __shared__ __align__(16) float red[12][64][4];           // wave1 partials (12 KB)
    __shared__ __align__(16) unsigned short epi[64 * 24];    // epilogue scratch (wave0)

    unsigned short* sm = &stg[w][0];

    f32x4 acc[12] = {};
    float4_t xsA[4], xsB[4];

    auto gloadA = [&](int t) {
        const float* p = xb + (size_t)(cb + t * 64 + l) * Nd;
        #pragma unroll
        for (int i = 0; i < 4; ++i) xsA[i] = *(const float4_t*)(p + i * 4);
    };
    auto gloadB = [&](int t) {
        const float* p = xb + (size_t)(cb + t * 64 + l) * Nd;
        #pragma unroll
        for (int i = 0; i < 4; ++i) xsB[i] = *(const float4_t*)(p + i * 4);
    };
    auto dswriteA = [&]() {     // transpose: sm[n-local i][c-local l]
        #pragma unroll
        for (int i = 0; i < 16; ++i)
            sm[i * 72 + l] = f2bf(xsA[i >> 2][i & 3]);
    };
    auto dswriteB = [&]() {
        #pragma unroll
        for (int i = 0; i < 16; ++i)
            sm[i * 72 + l] = f2bf(xsB[i >> 2][i & 3]);
    };
    auto compute = [&](int t) {
        #pragma unroll
        for (int kk = 0; kk < 2; ++kk) {
            bf16x8 af = ld_bf8(&sm[lo * 72 + kk * 32 + hi * 8]);
            #pragma unroll
            for (int j = 0; j < 12; ++j) {
                const unsigned short* wm = w4 + (j >> 2) * 32768;
                bf16x8 bf = ld_bf8(wm + ((j & 3) * 16 + lo) * Cd + cb + t * 64 + kk * 32 + hi * 8);
                acc[j] = mfma16(af, bf, acc[j]);
            }
        }
    };

    gloadA(0);
    gloadB(1);
    for (int t = 0; t < 4; t += 2) {
        dswriteA();                              // tile t (waits only its own regs)
        asm volatile("" ::: "memory");
        if (t + 2 < 4) gloadA(t + 2);
        __builtin_amdgcn_sched_barrier(0);       // pin loads (validated pattern)
        compute(t);
        asm volatile("" ::: "memory");           // reads before overwrite (in-order DS)
        dswriteB();                              // tile t+1
        asm volatile("" ::: "memory");
        if (t + 3 < 4) gloadB(t + 3);
        __builtin_amdgcn_sched_barrier(0);
        compute(t + 1);
        asm volatile("" ::: "memory");
    }

    // ---- cross-wave reduce (single barrier in kernel) ----
    if (w == 1) {
        #pragma unroll
        for (int j = 0; j < 12; ++j)
            *(f32x4*)&red[j][l][0] = acc[j];
    }
    __syncthreads();
    if (w == 1) return;

    #pragma unroll
    for (int j = 0; j < 12; ++j)
        acc[j] += *(const f32x4*)&red[j][l][0];

    // ---- epilogue: q, k via per-wave LDS transpose (validated v6 pattern) ----
    #pragma unroll
    for (int m = 0; m < 2; ++m) {
        const float* bias = m ? bk : bq;
        #pragma unroll
        for (int j = 0; j < 4; ++j) {
            const float bia = bias[j * 16 + lo];
            #pragma unroll
            for (int r = 0; r < 4; ++r)
                epi[(hi * 4 + r) * 72 + j * 16 + lo] = f2bf(acc[m * 4 + j][r] + bia);
        }
        asm volatile("" ::: "memory");
        const int row = l >> 2, dg = l & 3;
        ushort8_t a0 = *(const ushort8_t*)&epi[row * 72 + dg * 16];
        ushort8_t a1 = *(const ushort8_t*)&epi[row * 72 + dg * 16 + 8];
        unsigned short* dst = (m ? k_nd : q_nd)
            + ((size_t)b * Nd + n0w + row) * 64 + dg * 16;
        *(ushort8_t*)dst = a0; *(ushort8_t*)(dst + 8) = a1;
        asm volatile("" ::: "memory");           // m=0 reads before m=1 overwrites
    }

    // ---- epilogue: v via [64d][24] transpose, 32B d-row stores ----
    #pragma unroll
    for (int j = 0; j < 4; ++j) {
        const float bia = bv[j * 16 + lo];
        #pragma unroll
        for (int r = 0; r < 4; ++r)
            epi[(j * 16 + lo) * 24 + hi * 4 + r] = f2bf(acc[8 + j][r] + bia);
    }
    asm volatile("" ::: "memory");
    {
        ushort8_t a0 = *(const ushort8_t*)&epi[l * 24];
        ushort8_t a1 = *(const ushort8_t*)&epi[l * 24 + 8];
        unsigned short* dst = v_dn + ((size_t)b * Dd + l) * Nd + n0w;
        *(ushort8_t*)dst = a0; *(ushort8_t*)(dst + 8) = a1;
    }
}

// ---------------- K2: flash attention, 2qh x 2kh wave split (round-6/9 validated, 62.7us) ----
__global__ __launch_bounds__(256, 2) void k_attn(
    const unsigned short* __restrict__ q_nd,
    const unsigned short* __restrict__ k_nd,
    const unsigned short* __restrict__ v_dn,
    unsigned short* __restrict__ o_nd)
{
    const int bid = blockIdx.x;
    const int b   = bid & 7;            // round-robin XCD dispatch -> batch-per-XCD L2 locality
    const int n0  = (bid >> 3) * 64;
    const int tid = threadIdx.x, wid = tid >> 6, l = tid & 63;
    const int lo  = l & 15, hi = l >> 4;
    const int lsw = lo & 7;
    const int qh  = wid >> 1;           // q-half (32 rows)
    const int kh  = wid & 1;            // key-half (32 keys)
    const int wk0 = kh * 32;

    __shared__ unsigned short k_tiles[2][64 * 64];
    __shared__ unsigned short v_tiles[2][64 * 64];
    __shared__ float red_acc[2][2][4][256];   // [qh][qs][ds][lane*4]
    __shared__ float red_l[2][2][16];         // [qh][qs][lo]

    const unsigned short* qb = q_nd + (size_t)b * Nd * Dd;
    const unsigned short* kb = k_nd + (size_t)b * Nd * Dd;
    const unsigned short* vb = v_dn + (size_t)b * Dd * Nd;

    bf16x8 aq[2][2];
    #pragma unroll
    for (int qs = 0; qs < 2; ++qs)
        #pragma unroll
        for (int kc = 0; kc < 2; ++kc)
            aq[qs][kc] = ld_bf8(qb + (size_t)(n0 + qh*32 + qs*16 + lo) * 64 + kc*32 + hi*8);

    f32x4 acc[2][4] = {};
    float l_p[2] = {0.f, 0.f};

    const int sr = tid >> 3, ss = tid & 7;
    const int kwsl = (ss ^ (sr & 7)) * 8;
    const int vkh = ss >> 2, vsl = ss & 3, vms = vsl >> 1;
    const int vg0 = vkh * 4 + ((2 * vsl) & 3);
    const int vg1 = vkh * 4 + ((2 * vsl + 1) & 3);
    const int vsw = sr & 7;
    ushort8_t kr0, kr1, vr0, vr1;

    auto gload = [&](int t) {
        const size_t m1 = (size_t)t * 64;
        kr0 = *(const ushort8_t*)(kb + (m1 + sr) * 64 + ss * 8);
        kr1 = *(const ushort8_t*)(kb + (m1 + 32 + sr) * 64 + ss * 8);
        vr0 = *(const ushort8_t*)(vb + (size_t)sr * Nd + m1 + ss * 8);
        vr1 = *(const ushort8_t*)(vb + (size_t)(32 + sr) * Nd + m1 + ss * 8);
    };
    auto dswrite = [&](int buf) {
        unsigned short* kt = k_tiles[buf];
        unsigned short* vt = v_tiles[buf];
        *(ushort8_t*)(kt + sr * 64 + kwsl)        = kr0;
        *(ushort8_t*)(kt + (32 + sr) * 64 + kwsl) = kr1;
        ushort4_t a0 = __builtin_shufflevector(vr0, vr0, 0, 1, 2, 3);
        ushort4_t a1 = __builtin_shufflevector(vr0, vr0, 4, 5, 6, 7);
        ushort4_t b0 = __builtin_shufflevector(vr1, vr1, 0, 1, 2, 3);
        ushort4_t b1 = __builtin_shufflevector(vr1, vr1, 4, 5, 6, 7);
        *(ushort4_t*)(vt + sr * 64 + (vg0 ^ vsw) * 8 + vms * 4)        = a0;
        *(ushort4_t*)(vt + sr * 64 + (vg1 ^ vsw) * 8 + vms * 4)        = a1;
        *(ushort4_t*)(vt + (32 + sr) * 64 + (vg0 ^ vsw) * 8 + vms * 4) = b0;
        *(ushort4_t*)(vt + (32 + sr) * 64 + (vg1 ^ vsw) * 8 + vms * 4) = b1;
    };

    auto compute = [&](int buf) {
        const unsigned short* kt = k_tiles[buf];
        const unsigned short* vt = v_tiles[buf];
        f32x4 s[2][2] = {};
        #pragma unroll
        for (int ms = 0; ms < 2; ++ms) {
            #pragma unroll
            for (int kc = 0; kc < 2; ++kc) {
                bf16x8 kf = ld_bf8(kt + (wk0 + ms*16 + lo) * 64 + (((kc*4 + hi) ^ lsw) * 8));
                #pragma unroll
                for (int qs = 0; qs < 2; ++qs)
                    s[qs][ms] = mfma16(kf, aq[qs][kc], s[qs][ms]);
            }
        }
        bf16x8 vf[4];
        #pragma unroll
        for (int ds = 0; ds < 4; ++ds)
            vf[ds] = ld_bf8(vt + (ds*16 + lo) * 64 + (((kh*4 + hi) ^ lsw) * 8));
        #pragma unroll
        for (int qs = 0; qs < 2; ++qs) {
            float p[2][4];
            #pragma unroll
            for (int ms = 0; ms < 2; ++ms)
                #pragma unroll
                for (int r = 0; r < 4; ++r)
                    p[ms][r] = __expf(s[qs][ms][r]);
            l_p[qs] += ((p[0][0] + p[0][1]) + (p[0][2] + p[0][3]))
                     + ((p[1][0] + p[1][1]) + (p[1][2] + p[1][3]));
            uint4_t w;
            w[0] = pack2(p[0][0], p[0][1]);
            w[1] = pack2(p[0][2], p[0][3]);
            w[2] = pack2(p[1][0], p[1][1]);
            w[3] = pack2(p[1][2], p[1][3]);
            bf16x8 apf = __builtin_bit_cast(bf16x8, w);
            #pragma unroll
            for (int ds = 0; ds < 4; ++ds)
                acc[qs][ds] = mfma16(apf, vf[ds], acc[qs][ds]);
        }
    };

    constexpr int NT = Nd / 64;
    gload(0);
    dswrite(0);
    __syncthreads();
    for (int t = 0; t < NT; ++t) {
        const int cur = t & 1;
        if (t + 1 < NT) gload(t + 1);
        __builtin_amdgcn_sched_barrier(0);
        compute(cur);
        if (t + 1 < NT) dswrite(cur ^ 1);
        __syncthreads();
    }

    float lh[2];
    #pragma unroll
    for (int qs = 0; qs < 2; ++qs) {
        float ps = l_p[qs];
        ps += __shfl_xor(ps, 16, 64);
        ps += __shfl_xor(ps, 32, 64);
        lh[qs] = ps;
    }
    if (kh == 1) {
        #pragma unroll
        for (int qs = 0; qs < 2; ++qs) {
            #pragma unroll
            for (int ds = 0; ds < 4; ++ds)
                *(f32x4*)&red_acc[qh][qs][ds][l * 4] = acc[qs][ds];
            red_l[qh][qs][lo] = lh[qs];
        }
    }
    __syncthreads();
    if (kh == 0) {
        #pragma unroll
        for (int qs = 0; qs < 2; ++qs) {
            #pragma unroll
            for (int ds = 0; ds < 4; ++ds)
                acc[qs][ds] += *(const f32x4*)&red_acc[qh][qs][ds][l * 4];
            float l_tot = lh[qs] + red_l[qh][qs][lo];
            #pragma unroll
            for (int r = 0; r < 4; ++r) {
                float lq = __shfl(l_tot, hi * 4 + r, 16);
                float rl = 1.0f / lq;
                #pragma unroll
                for (int ds = 0; ds < 4; ++ds) {
                    float o = acc[qs][ds][r] * rl;
                    o_nd[((size_t)b * Nd + n0 + qh*32 + qs*16 + hi*4 + r) * 64 + ds*16 + lo] = f2bf(o);
                }
            }
        }
    }
}

// ---------------- K3: output projection + residual ----------------
__global__ __launch_bounds__(256) void k_oproj(
    const unsigned short* __restrict__ o_nd,
    const unsigned short* __restrict__ wo,
    const float* __restrict__ bo,
    const float* __restrict__ gamma,
    const float* __restrict__ x,
    float* __restrict__ out)
{
    const int b   = blockIdx.y;
    const int n0  = blockIdx.x * 64;
    const int tid = threadIdx.x, wid = tid >> 6, l = tid & 63;
    const int lo  = l & 15, hi = l >> 4;
    const int n0w = n0 + wid * 16;
    const float g = gamma[0];

    bf16x8 ao[2];
    #pragma unroll
    for (int kc = 0; kc < 2; ++kc)
        ao[kc] = ld_bf8(o_nd + ((size_t)b * Nd + n0w + lo) * 64 + kc*32 + hi*8);

    for (int ct = 0; ct < 32; ++ct) {
        f32x4 acc = {};
        #pragma unroll
        for (int kc = 0; kc < 2; ++kc) {
            bf16x8 bw = ld_bf8(wo + (ct*16 + lo) * 64 + kc*32 + hi*8);
            acc = mfma16(ao[kc], bw, acc);
        }
        const int c = ct*16 + lo;
        const float bc = bo[c];
        const size_t base = ((size_t)b * Cd + c) * Nd + n0w + hi*4;
        float4_t xv = *(const float4_t*)(x + base);
        float4_t ov;
        #pragma unroll
        for (int r = 0; r < 4; ++r) ov[r] = g * (acc[r] + bc) + xv[r];
        *(float4_t*)(out + base) = ov;
    }
}

extern "C" void kernel_launch(void* const* d_in, const int* in_sizes, int n_in,
                              void* d_out, int out_size, void* d_ws, size_t ws_size,
                              hipStream_t stream) {
    (void)in_sizes; (void)n_in; (void)out_size; (void)ws_size;
    const float* x  = (const float*)d_in[0];
    const float* Wq = (const float*)d_in[1];
    const float* bq = (const float*)d_in[2];
    const float* Wk = (const float*)d_in[3];
    const float* bk = (const float*)d_in[4];
    const float* Wv = (const float*)d_in[5];
    const float* bv = (const float*)d_in[6];
    const float* Wo = (const float*)d_in[7];
    const float* bo = (const float*)d_in[8];
    const float* gm = (const float*)d_in[9];
    float* out = (float*)d_out;

    unsigned short* w4   = (unsigned short*)d_ws;          // 4 x 32768 bf16 weights
    unsigned short* q_nd = w4 + 131072;
    unsigned short* k_nd = q_nd + (size_t)Bd * Nd * Dd;
    unsigned short* v_dn = k_nd + (size_t)Bd * Nd * Dd;
    unsigned short* o_nd = v_dn + (size_t)Bd * Nd * Dd;

    k_cvtw<<<128, 256, 0, stream>>>(Wq, Wk, Wv, Wo, w4);
    dim3 gq(Nd / 16, Bd);
    k_qkv<<<gq, 128, 0, stream>>>(x, w4, bq, bk, bv, q_nd, k_nd, v_dn);
    k_attn<<<512, 256, 0, stream>>>(q_nd, k_nd, v_dn, o_nd);
    dim3 g1(Nd / 64, Bd);
    k_oproj<<<g1, 256, 0, stream>>>(o_nd, w4 + 98304, bo, gm, x, out);
}

// Round 14
// 146.361 us; speedup vs baseline: 1.3240x; 1.0676x over previous
//
#include <hip/hip_runtime.h>
#include <hip/hip_bf16.h>

#define DEVFN __device__ __forceinline__

typedef __bf16 bf16x8 __attribute__((ext_vector_type(8)));
typedef float f32x4 __attribute__((ext_vector_type(4)));
typedef float float4_t __attribute__((ext_vector_type(4)));
typedef unsigned short ushort8_t __attribute__((ext_vector_type(8)));
typedef unsigned short ushort4_t __attribute__((ext_vector_type(4)));
typedef unsigned int uint4_t __attribute__((ext_vector_type(4)));

constexpr int Bd = 8, Cd = 512, Nd = 4096, Dd = 64;

DEVFN unsigned short f2bf(float f) {
    union { float f; unsigned int u; } v; v.f = f;
    unsigned int r = (v.u + 0x7FFFu + ((v.u >> 16) & 1u)) >> 16;
    return (unsigned short)r;
}

DEVFN unsigned int pack2(float a, float b) {   // two f32 -> packed bf16x2 (RNE)
    __hip_bfloat162 h = __float22bfloat162_rn(make_float2(a, b));
    union { __hip_bfloat162 h; unsigned int u; } c; c.h = h;
    return c.u;
}

DEVFN bf16x8 ld_bf8(const unsigned short* p) {
    ushort8_t u = *(const ushort8_t*)p;
    return __builtin_bit_cast(bf16x8, u);
}

DEVFN f32x4 mfma16(bf16x8 a, bf16x8 b, f32x4 c) {
    return __builtin_amdgcn_mfma_f32_16x16x32_bf16(a, b, c, 0, 0, 0);
}

// ---------------- K0: convert weights to bf16 ----------------
__global__ __launch_bounds__(256) void k_cvtw(
    const float* __restrict__ Wq, const float* __restrict__ Wk,
    const float* __restrict__ Wv, const float* __restrict__ Wo,
    unsigned short* __restrict__ w4)
{
    int i = blockIdx.x * 256 + threadIdx.x;   // 0..32767
    w4[i]          = f2bf(Wq[i]);
    w4[32768 + i]  = f2bf(Wk[i]);
    w4[65536 + i]  = f2bf(Wv[i]);
    w4[98304 + i]  = f2bf(Wo[i]);
}

// ---------------- K1: QKV (round-9 v4, measured best 63.4us, restored verbatim) ----------------
__global__ __launch_bounds__(128, 2) void k_qkv(
    const float* __restrict__ x,
    const unsigned short* __restrict__ wq,
    const unsigned short* __restrict__ wk,
    const unsigned short* __restrict__ wv,
    const float* __restrict__ bq, const float* __restrict__ bk, const float* __restrict__ bv,
    unsigned short* __restrict__ q_nd, unsigned short* __restrict__ k_nd,
    unsigned short* __restrict__ v_dn)
{
    const int b   = blockIdx.y;
    const int n0  = blockIdx.x * 32;
    const int tid = threadIdx.x, wid = tid >> 6, l = tid & 63;
    const int lo  = l & 15, hi = l >> 4;
    const float* xb = x + (size_t)b * Cd * Nd;

    __shared__ unsigned short smem[2][32][72];   // xt double-buffer; reused by epilogue

    f32x4 acc[12] = {};

    const int scr = tid >> 3;      // 0..15
    const int snf = tid & 7;       // 0..7
    float4_t xrA[4], xrB[4];

    auto gloadA = [&](int t) {
        const int c0 = t * 64;
        #pragma unroll
        for (int p = 0; p < 4; ++p)
            xrA[p] = *(const float4_t*)(xb + (size_t)(c0 + p*16 + scr) * Nd + n0 + snf*4);
    };
    auto gloadB = [&](int t) {
        const int c0 = t * 64;
        #pragma unroll
        for (int p = 0; p < 4; ++p)
            xrB[p] = *(const float4_t*)(xb + (size_t)(c0 + p*16 + scr) * Nd + n0 + snf*4);
    };
    auto dswriteA = [&](int buf) {
        #pragma unroll
        for (int p = 0; p < 4; ++p)
            #pragma unroll
            for (int i = 0; i < 4; ++i)
                smem[buf][snf*4 + i][p*16 + scr] = f2bf(xrA[p][i]);
    };
    auto dswriteB = [&](int buf) {
        #pragma unroll
        for (int p = 0; p < 4; ++p)
            #pragma unroll
            for (int i = 0; i < 4; ++i)
                smem[buf][snf*4 + i][p*16 + scr] = f2bf(xrB[p][i]);
    };
    auto compute = [&](int buf, int t) {
        const int c0 = t * 64;
        #pragma unroll
        for (int kk = 0; kk < 2; ++kk) {
            bf16x8 af = ld_bf8(&smem[buf][wid*16 + lo][kk*32 + hi*8]);
            #pragma unroll
            for (int j = 0; j < 12; ++j) {
                const unsigned short* wm = (j < 4) ? wq : (j < 8) ? wk : wv;
                const int d0 = (j & 3) * 16;
                bf16x8 bf = ld_bf8(wm + (d0 + lo) * Cd + c0 + kk*32 + hi*8);
                acc[j] = mfma16(af, bf, acc[j]);
            }
        }
    };

    gloadA(0);
    dswriteA(0);
    gloadB(1);
    __syncthreads();
    for (int t = 0; t < 8; t += 2) {
        if (t + 2 < 8) gloadA(t + 2);            // prefetch 2 ahead
        __builtin_amdgcn_sched_barrier(0);
        compute(0, t);
        dswriteB(1);
        __syncthreads();
        if (t + 3 < 8) gloadB(t + 3);
        __builtin_amdgcn_sched_barrier(0);
        compute(1, t + 1);
        if (t + 2 < 8) dswriteA(0);
        __syncthreads();
    }

    // ---- epilogue: q/k via per-wave transpose (smem[1], wave-private 16 rows) ----
    unsigned short* tl = &smem[1][wid*16][0];    // [16 n-local][72]
    #pragma unroll
    for (int m = 0; m < 2; ++m) {
        const float* bias = m ? bk : bq;
        #pragma unroll
        for (int jj = 0; jj < 4; ++jj) {
            const float bia = bias[jj*16 + lo];
            #pragma unroll
            for (int r = 0; r < 4; ++r)
                tl[(hi*4 + r) * 72 + jj*16 + lo] = f2bf(acc[m*4 + jj][r] + bia);
        }
        asm volatile("" ::: "memory");
        const int row = l >> 2, dg = l & 3;
        ushort8_t a0 = *(const ushort8_t*)&tl[row*72 + dg*16];
        ushort8_t a1 = *(const ushort8_t*)&tl[row*72 + dg*16 + 8];
        unsigned short* dst = (m ? k_nd : q_nd)
            + ((size_t)b * Nd + n0 + wid*16 + row) * 64 + dg*16;
        *(ushort8_t*)dst = a0; *(ushort8_t*)(dst + 8) = a1;
        asm volatile("" ::: "memory");
    }

    // ---- epilogue: v via block-wide transpose (smem[0] viewed as [64][36]) ----
    unsigned short* vt = &smem[0][0][0];
    #pragma unroll
    for (int jj = 0; jj < 4; ++jj) {
        const float bia = bv[jj*16 + lo];
        #pragma unroll
        for (int r = 0; r < 4; ++r)
            vt[(jj*16 + lo) * 36 + wid*16 + hi*4 + r] = f2bf(acc[8 + jj][r] + bia);
    }
    __syncthreads();
    #pragma unroll
    for (int p = 0; p < 2; ++p) {
        const int d = p*32 + (tid >> 2), ng = tid & 3;
        ushort4_t a0 = *(const ushort4_t*)&vt[d*36 + ng*8];
        ushort4_t a1 = *(const ushort4_t*)&vt[d*36 + ng*8 + 4];
        unsigned short* dst = v_dn + ((size_t)b * Dd + d) * Nd + n0 + ng*8;
        *(ushort4_t*)dst = a0; *(ushort4_t*)(dst + 4) = a1;
    }
}

// ---------------- K2 v4: flash attention, 512 thr = 4qh x 2kh, 16 waves/CU ----------------
// Same traffic as r6 (64q blocks, grid 512, full K/V stream per block) but 8
// waves/block -> 4 waves/SIMD: 2x latency hiding for the ds_read->MFMA->exp
// chains. Wave-level code = r10's validated 16q x 32key structure.
__global__ __launch_bounds__(512, 4) void k_attn(
    const unsigned short* __restrict__ q_nd,
    const unsigned short* __restrict__ k_nd,
    const unsigned short* __restrict__ v_dn,
    unsigned short* __restrict__ o_nd)
{
    const int bid = blockIdx.x;
    const int b   = bid & 7;            // round-robin XCD dispatch -> batch-per-XCD L2 locality
    const int n0  = (bid >> 3) * 64;
    const int tid = threadIdx.x, wid = tid >> 6, l = tid & 63;
    const int lo  = l & 15, hi = l >> 4;
    const int lsw = lo & 7;
    const int qh  = wid >> 1;           // q-subtile 0..3 (16 rows each)
    const int kh  = wid & 1;            // key-half (32 keys)
    const int wk0 = kh * 32;

    __shared__ unsigned short k_tiles[2][64 * 64];
    __shared__ unsigned short v_tiles[2][64 * 64];
    __shared__ float red_acc[4][4][256];     // [qh][ds][lane*4] = 16 KB
    __shared__ float red_l[4][16];

    const unsigned short* qb = q_nd + (size_t)b * Nd * Dd;
    const unsigned short* kb = k_nd + (size_t)b * Nd * Dd;
    const unsigned short* vb = v_dn + (size_t)b * Dd * Nd;

    bf16x8 aq[2];
    #pragma unroll
    for (int kc = 0; kc < 2; ++kc)
        aq[kc] = ld_bf8(qb + (size_t)(n0 + qh*16 + lo) * 64 + kc*32 + hi*8);

    f32x4 acc[4] = {};
    float l_p = 0.f;

    // staging: 512 threads -> row sr (0..63), slot ss; 16B of K + 16B of V each
    const int sr = tid >> 3, ss = tid & 7;
    const int kwsl = (ss ^ (sr & 7)) * 8;
    const int vkh = ss >> 2, vsl = ss & 3, vms = vsl >> 1;
    const int vg0 = vkh * 4 + ((2 * vsl) & 3);
    const int vg1 = vkh * 4 + ((2 * vsl + 1) & 3);
    const int vsw = sr & 7;
    ushort8_t kr, vr;

    auto gload = [&](int t) {
        const size_t m1 = (size_t)t * 64;
        kr = *(const ushort8_t*)(kb + (m1 + sr) * 64 + ss * 8);
        vr = *(const ushort8_t*)(vb + (size_t)sr * Nd + m1 + ss * 8);
    };
    auto dswrite = [&](int buf) {
        unsigned short* kt = k_tiles[buf];
        unsigned short* vt = v_tiles[buf];
        *(ushort8_t*)(kt + sr * 64 + kwsl) = kr;
        ushort4_t a0 = __builtin_shufflevector(vr, vr, 0, 1, 2, 3);
        ushort4_t a1 = __builtin_shufflevector(vr, vr, 4, 5, 6, 7);
        *(ushort4_t*)(vt + sr * 64 + (vg0 ^ vsw) * 8 + vms * 4) = a0;
        *(ushort4_t*)(vt + sr * 64 + (vg1 ^ vsw) * 8 + vms * 4) = a1;
    };

    auto compute = [&](int buf) {
        const unsigned short* kt = k_tiles[buf];
        const unsigned short* vt = v_tiles[buf];
        f32x4 s[2] = {};
        #pragma unroll
        for (int ms = 0; ms < 2; ++ms) {
            #pragma unroll
            for (int kc = 0; kc < 2; ++kc) {
                bf16x8 kf = ld_bf8(kt + (wk0 + ms*16 + lo) * 64 + (((kc*4 + hi) ^ lsw) * 8));
                s[ms] = mfma16(kf, aq[kc], s[ms]);
            }
        }
        bf16x8 vf[4];
        #pragma unroll
        for (int ds = 0; ds < 4; ++ds)
            vf[ds] = ld_bf8(vt + (ds*16 + lo) * 64 + (((kh*4 + hi) ^ lsw) * 8));
        float p[2][4];
        #pragma unroll
        for (int ms = 0; ms < 2; ++ms)
            #pragma unroll
            for (int r = 0; r < 4; ++r)
                p[ms][r] = __expf(s[ms][r]);
        l_p += ((p[0][0] + p[0][1]) + (p[0][2] + p[0][3]))
             + ((p[1][0] + p[1][1]) + (p[1][2] + p[1][3]));
        uint4_t w;
        w[0] = pack2(p[0][0], p[0][1]);
        w[1] = pack2(p[0][2], p[0][3]);
        w[2] = pack2(p[1][0], p[1][1]);
        w[3] = pack2(p[1][2], p[1][3]);
        bf16x8 apf = __builtin_bit_cast(bf16x8, w);
        #pragma unroll
        for (int ds = 0; ds < 4; ++ds)
            acc[ds] = mfma16(apf, vf[ds], acc[ds]);
    };

    constexpr int NT = Nd / 64;
    gload(0);
    dswrite(0);
    __syncthreads();
    for (int t = 0; t < NT; ++t) {
        const int cur = t & 1;
        if (t + 1 < NT) gload(t + 1);
        __builtin_amdgcn_sched_barrier(0);
        compute(cur);
        if (t + 1 < NT) dswrite(cur ^ 1);
        __syncthreads();
    }

    // ---- epilogue: cross-kh reduce, normalize, store (r10-validated pattern) ----
    float lh = l_p;
    lh += __shfl_xor(lh, 16, 64);
    lh += __shfl_xor(lh, 32, 64);               // l over this wave's 32 keys, q = base+lo
    if (kh == 1) {
        #pragma unroll
        for (int ds = 0; ds < 4; ++ds)
            *(f32x4*)&red_acc[qh][ds][l * 4] = acc[ds];
        red_l[qh][lo] = lh;
    }
    __syncthreads();
    if (kh == 0) {
        #pragma unroll
        for (int ds = 0; ds < 4; ++ds)
            acc[ds] += *(const f32x4*)&red_acc[qh][ds][l * 4];
        float l_tot = lh + red_l[qh][lo];
        #pragma unroll
        for (int r = 0; r < 4; ++r) {
            float lq = __shfl(l_tot, hi * 4 + r, 16);
            float rl = 1.0f / lq;
            #pragma unroll
            for (int ds = 0; ds < 4; ++ds) {
                float o = acc[ds][r] * rl;
                o_nd[((size_t)b * Nd + n0 + qh*16 + hi*4 + r) * 64 + ds*16 + lo] = f2bf(o);
            }
        }
    }
}

// ---------------- K3: output projection + residual ----------------
__global__ __launch_bounds__(256) void k_oproj(
    const unsigned short* __restrict__ o_nd,
    const unsigned short* __restrict__ wo,
    const float* __restrict__ bo,
    const float* __restrict__ gamma,
    const float* __restrict__ x,
    float* __restrict__ out)
{
    const int b   = blockIdx.y;
    const int n0  = blockIdx.x * 64;
    const int tid = threadIdx.x, wid = tid >> 6, l = tid & 63;
    const int lo  = l & 15, hi = l >> 4;
    const int n0w = n0 + wid * 16;
    const float g = gamma[0];

    bf16x8 ao[2];
    #pragma unroll
    for (int kc = 0; kc < 2; ++kc)
        ao[kc] = ld_bf8(o_nd + ((size_t)b * Nd + n0w + lo) * 64 + kc*32 + hi*8);

    for (int ct = 0; ct < 32; ++ct) {
        f32x4 acc = {};
        #pragma unroll
        for (int kc = 0; kc < 2; ++kc) {
            bf16x8 bw = ld_bf8(wo + (ct*16 + lo) * 64 + kc*32 + hi*8);
            acc = mfma16(ao[kc], bw, acc);
        }
        const int c = ct*16 + lo;
        const float bc = bo[c];
        const size_t base = ((size_t)b * Cd + c) * Nd + n0w + hi*4;
        float4_t xv = *(const float4_t*)(x + base);
        float4_t ov;
        #pragma unroll
        for (int r = 0; r < 4; ++r) ov[r] = g * (acc[r] + bc) + xv[r];
        *(float4_t*)(out + base) = ov;
    }
}

extern "C" void kernel_launch(void* const* d_in, const int* in_sizes, int n_in,
                              void* d_out, int out_size, void* d_ws, size_t ws_size,
                              hipStream_t stream) {
    (void)in_sizes; (void)n_in; (void)out_size; (void)ws_size;
    const float* x  = (const float*)d_in[0];
    const float* Wq = (const float*)d_in[1];
    const float* bq = (const float*)d_in[2];
    const float* Wk = (const float*)d_in[3];
    const float* bk = (const float*)d_in[4];
    const float* Wv = (const float*)d_in[5];
    const float* bv = (const float*)d_in[6];
    const float* Wo = (const float*)d_in[7];
    const float* bo = (const float*)d_in[8];
    const float* gm = (const float*)d_in[9];
    float* out = (float*)d_out;

    unsigned short* w4   = (unsigned short*)d_ws;          // 4 x 32768 bf16 weights
    unsigned short* q_nd = w4 + 131072;
    unsigned short* k_nd = q_nd + (size_t)Bd * Nd * Dd;
    unsigned short* v_dn = k_nd + (size_t)Bd * Nd * Dd;
    unsigned short* o_nd = v_dn + (size_t)Bd * Nd * Dd;

    k_cvtw<<<128, 256, 0, stream>>>(Wq, Wk, Wv, Wo, w4);
    dim3 gq(Nd / 32, Bd);
    k_qkv<<<gq, 128, 0, stream>>>(x, w4, w4 + 32768, w4 + 65536, bq, bk, bv, q_nd, k_nd, v_dn);
    k_attn<<<512, 512, 0, stream>>>(q_nd, k_nd, v_dn, o_nd);
    dim3 g1(Nd / 64, Bd);
    k_oproj<<<g1, 256, 0, stream>>>(o_nd, w4 + 98304, bo, gm, x, out);
}

// Round 15
// 142.475 us; speedup vs baseline: 1.3601x; 1.0273x over previous
//
#include <hip/hip_runtime.h>
#include <hip/hip_bf16.h>

#define DEVFN __device__ __forceinline__

typedef __bf16 bf16x8 __attribute__((ext_vector_type(8)));
typedef float f32x4 __attribute__((ext_vector_type(4)));
typedef float float4_t __attribute__((ext_vector_type(4)));
typedef unsigned short ushort8_t __attribute__((ext_vector_type(8)));
typedef unsigned short ushort4_t __attribute__((ext_vector_type(4)));
typedef unsigned int uint4_t __attribute__((ext_vector_type(4)));

constexpr int Bd = 8, Cd = 512, Nd = 4096, Dd = 64;

DEVFN unsigned short f2bf(float f) {
    union { float f; unsigned int u; } v; v.f = f;
    unsigned int r = (v.u + 0x7FFFu + ((v.u >> 16) & 1u)) >> 16;
    return (unsigned short)r;
}

DEVFN unsigned int pack2(float a, float b) {   // two f32 -> packed bf16x2 (RNE)
    __hip_bfloat162 h = __float22bfloat162_rn(make_float2(a, b));
    union { __hip_bfloat162 h; unsigned int u; } c; c.h = h;
    return c.u;
}

DEVFN bf16x8 ld_bf8(const unsigned short* p) {
    ushort8_t u = *(const ushort8_t*)p;
    return __builtin_bit_cast(bf16x8, u);
}

DEVFN f32x4 mfma16(bf16x8 a, bf16x8 b, f32x4 c) {
    return __builtin_amdgcn_mfma_f32_16x16x32_bf16(a, b, c, 0, 0, 0);
}

// ---------------- K0: convert weights to bf16 ----------------
__global__ __launch_bounds__(256) void k_cvtw(
    const float* __restrict__ Wq, const float* __restrict__ Wk,
    const float* __restrict__ Wv, const float* __restrict__ Wo,
    unsigned short* __restrict__ w4)
{
    int i = blockIdx.x * 256 + threadIdx.x;   // 0..32767
    w4[i]          = f2bf(Wq[i]);
    w4[32768 + i]  = f2bf(Wk[i]);
    w4[65536 + i]  = f2bf(Wv[i]);
    w4[98304 + i]  = f2bf(Wo[i]);
}

// ---------------- K1: QKV (round-9 v4, measured best ~63us, unchanged) ----------------
__global__ __launch_bounds__(128, 2) void k_qkv(
    const float* __restrict__ x,
    const unsigned short* __restrict__ wq,
    const unsigned short* __restrict__ wk,
    const unsigned short* __restrict__ wv,
    const float* __restrict__ bq, const float* __restrict__ bk, const float* __restrict__ bv,
    unsigned short* __restrict__ q_nd, unsigned short* __restrict__ k_nd,
    unsigned short* __restrict__ v_dn)
{
    const int b   = blockIdx.y;
    const int n0  = blockIdx.x * 32;
    const int tid = threadIdx.x, wid = tid >> 6, l = tid & 63;
    const int lo  = l & 15, hi = l >> 4;
    const float* xb = x + (size_t)b * Cd * Nd;

    __shared__ unsigned short smem[2][32][72];   // xt double-buffer; reused by epilogue

    f32x4 acc[12] = {};

    const int scr = tid >> 3;      // 0..15
    const int snf = tid & 7;       // 0..7
    float4_t xrA[4], xrB[4];

    auto gloadA = [&](int t) {
        const int c0 = t * 64;
        #pragma unroll
        for (int p = 0; p < 4; ++p)
            xrA[p] = *(const float4_t*)(xb + (size_t)(c0 + p*16 + scr) * Nd + n0 + snf*4);
    };
    auto gloadB = [&](int t) {
        const int c0 = t * 64;
        #pragma unroll
        for (int p = 0; p < 4; ++p)
            xrB[p] = *(const float4_t*)(xb + (size_t)(c0 + p*16 + scr) * Nd + n0 + snf*4);
    };
    auto dswriteA = [&](int buf) {
        #pragma unroll
        for (int p = 0; p < 4; ++p)
            #pragma unroll
            for (int i = 0; i < 4; ++i)
                smem[buf][snf*4 + i][p*16 + scr] = f2bf(xrA[p][i]);
    };
    auto dswriteB = [&](int buf) {
        #pragma unroll
        for (int p = 0; p < 4; ++p)
            #pragma unroll
            for (int i = 0; i < 4; ++i)
                smem[buf][snf*4 + i][p*16 + scr] = f2bf(xrB[p][i]);
    };
    auto compute = [&](int buf, int t) {
        const int c0 = t * 64;
        #pragma unroll
        for (int kk = 0; kk < 2; ++kk) {
            bf16x8 af = ld_bf8(&smem[buf][wid*16 + lo][kk*32 + hi*8]);
            #pragma unroll
            for (int j = 0; j < 12; ++j) {
                const unsigned short* wm = (j < 4) ? wq : (j < 8) ? wk : wv;
                const int d0 = (j & 3) * 16;
                bf16x8 bf = ld_bf8(wm + (d0 + lo) * Cd + c0 + kk*32 + hi*8);
                acc[j] = mfma16(af, bf, acc[j]);
            }
        }
    };

    gloadA(0);
    dswriteA(0);
    gloadB(1);
    __syncthreads();
    for (int t = 0; t < 8; t += 2) {
        if (t + 2 < 8) gloadA(t + 2);            // prefetch 2 ahead
        __builtin_amdgcn_sched_barrier(0);
        compute(0, t);
        dswriteB(1);
        __syncthreads();
        if (t + 3 < 8) gloadB(t + 3);
        __builtin_amdgcn_sched_barrier(0);
        compute(1, t + 1);
        if (t + 2 < 8) dswriteA(0);
        __syncthreads();
    }

    // ---- epilogue: q/k via per-wave transpose (smem[1], wave-private 16 rows) ----
    unsigned short* tl = &smem[1][wid*16][0];    // [16 n-local][72]
    #pragma unroll
    for (int m = 0; m < 2; ++m) {
        const float* bias = m ? bk : bq;
        #pragma unroll
        for (int jj = 0; jj < 4; ++jj) {
            const float bia = bias[jj*16 + lo];
            #pragma unroll
            for (int r = 0; r < 4; ++r)
                tl[(hi*4 + r) * 72 + jj*16 + lo] = f2bf(acc[m*4 + jj][r] + bia);
        }
        asm volatile("" ::: "memory");
        const int row = l >> 2, dg = l & 3;
        ushort8_t a0 = *(const ushort8_t*)&tl[row*72 + dg*16];
        ushort8_t a1 = *(const ushort8_t*)&tl[row*72 + dg*16 + 8];
        unsigned short* dst = (m ? k_nd : q_nd)
            + ((size_t)b * Nd + n0 + wid*16 + row) * 64 + dg*16;
        *(ushort8_t*)dst = a0; *(ushort8_t*)(dst + 8) = a1;
        asm volatile("" ::: "memory");
    }

    // ---- epilogue: v via block-wide transpose (smem[0] viewed as [64][36]) ----
    unsigned short* vt = &smem[0][0][0];
    #pragma unroll
    for (int jj = 0; jj < 4; ++jj) {
        const float bia = bv[jj*16 + lo];
        #pragma unroll
        for (int r = 0; r < 4; ++r)
            vt[(jj*16 + lo) * 36 + wid*16 + hi*4 + r] = f2bf(acc[8 + jj][r] + bia);
    }
    __syncthreads();
    #pragma unroll
    for (int p = 0; p < 2; ++p) {
        const int d = p*32 + (tid >> 2), ng = tid & 3;
        ushort4_t a0 = *(const ushort4_t*)&vt[d*36 + ng*8];
        ushort4_t a1 = *(const ushort4_t*)&vt[d*36 + ng*8 + 4];
        unsigned short* dst = v_dn + ((size_t)b * Dd + d) * Nd + n0 + ng*8;
        *(ushort4_t*)dst = a0; *(ushort4_t*)(dst + 4) = a1;
    }
}

// ---------------- K2 v5: flash attention, 128-key iterations, 8 waves = 2qh x 2kh x 2tp ----
// Wave (qh,kh,tp): 32 q-rows (qs-loop reuse, r6-validated) x 32 keys of tile
// parity tp. Per-wave work and per-block LDS traffic per key = r6 exactly;
// barriers halve (1 per 128 keys); occupancy 4 waves/SIMD (2x r6).
// Epilogue: 3 publishing groups (kh,tp != 0,0) overlaid on the dead tiles.
__global__ __launch_bounds__(512, 4) void k_attn(
    const unsigned short* __restrict__ q_nd,
    const unsigned short* __restrict__ k_nd,
    const unsigned short* __restrict__ v_dn,
    unsigned short* __restrict__ o_nd)
{
    const int bid = blockIdx.x;
    const int b   = bid & 7;            // round-robin XCD dispatch -> batch-per-XCD L2 locality
    const int n0  = (bid >> 3) * 64;
    const int tid = threadIdx.x, wid = tid >> 6, l = tid & 63;
    const int lo  = l & 15, hi = l >> 4;
    const int lsw = lo & 7;
    const int qh  = wid >> 2;           // q-half (32 rows)
    const int kh  = (wid >> 1) & 1;     // key-half within tile (32 keys)
    const int tp  = wid & 1;            // tile parity within the 128-key pair
    const int wk0 = kh * 32;

    // [kv][pairbuf][tp][64*64] = 64 KB; epilogue reduction overlays this (dead then)
    __shared__ __align__(16) unsigned short kv_lds[2][2][2][64 * 64];
    __shared__ float red_l[3][2][2][16];

    const unsigned short* qb = q_nd + (size_t)b * Nd * Dd;
    const unsigned short* kb = k_nd + (size_t)b * Nd * Dd;
    const unsigned short* vb = v_dn + (size_t)b * Dd * Nd;

    bf16x8 aq[2][2];
    #pragma unroll
    for (int qs = 0; qs < 2; ++qs)
        #pragma unroll
        for (int kc = 0; kc < 2; ++kc)
            aq[qs][kc] = ld_bf8(qb + (size_t)(n0 + qh*32 + qs*16 + lo) * 64 + kc*32 + hi*8);

    f32x4 acc[2][4] = {};
    float l_p[2] = {0.f, 0.f};

    // staging: 512 thr -> row sr (0..63), slot ss; per thread 16B K + 16B V per tile
    const int sr = tid >> 3, ss = tid & 7;
    const int kwsl = (ss ^ (sr & 7)) * 8;
    const int vkh = ss >> 2, vsl = ss & 3, vms = vsl >> 1;
    const int vg0 = vkh * 4 + ((2 * vsl) & 3);
    const int vg1 = vkh * 4 + ((2 * vsl + 1) & 3);
    const int vsw = sr & 7;
    ushort8_t kr0, kr1, vr0, vr1;     // tile0 / tile1 of the pair

    auto gload = [&](int it) {
        const size_t m1 = (size_t)it * 128;
        kr0 = *(const ushort8_t*)(kb + (m1 + sr) * 64 + ss * 8);
        kr1 = *(const ushort8_t*)(kb + (m1 + 64 + sr) * 64 + ss * 8);
        vr0 = *(const ushort8_t*)(vb + (size_t)sr * Nd + m1 + ss * 8);
        vr1 = *(const ushort8_t*)(vb + (size_t)sr * Nd + m1 + 64 + ss * 8);
    };
    auto dswrite = [&](int buf) {
        unsigned short* kt0 = &kv_lds[0][buf][0][0];
        unsigned short* kt1 = &kv_lds[0][buf][1][0];
        unsigned short* vt0 = &kv_lds[1][buf][0][0];
        unsigned short* vt1 = &kv_lds[1][buf][1][0];
        *(ushort8_t*)(kt0 + sr * 64 + kwsl) = kr0;
        *(ushort8_t*)(kt1 + sr * 64 + kwsl) = kr1;
        ushort4_t a0 = __builtin_shufflevector(vr0, vr0, 0, 1, 2, 3);
        ushort4_t a1 = __builtin_shufflevector(vr0, vr0, 4, 5, 6, 7);
        ushort4_t b0 = __builtin_shufflevector(vr1, vr1, 0, 1, 2, 3);
        ushort4_t b1 = __builtin_shufflevector(vr1, vr1, 4, 5, 6, 7);
        *(ushort4_t*)(vt0 + sr * 64 + (vg0 ^ vsw) * 8 + vms * 4) = a0;
        *(ushort4_t*)(vt0 + sr * 64 + (vg1 ^ vsw) * 8 + vms * 4) = a1;
        *(ushort4_t*)(vt1 + sr * 64 + (vg0 ^ vsw) * 8 + vms * 4) = b0;
        *(ushort4_t*)(vt1 + sr * 64 + (vg1 ^ vsw) * 8 + vms * 4) = b1;
    };

    auto compute = [&](int buf) {
        const unsigned short* kt = &kv_lds[0][buf][tp][0];
        const unsigned short* vt = &kv_lds[1][buf][tp][0];
        f32x4 s[2][2] = {};
        #pragma unroll
        for (int ms = 0; ms < 2; ++ms) {
            #pragma unroll
            for (int kc = 0; kc < 2; ++kc) {
                bf16x8 kf = ld_bf8(kt + (wk0 + ms*16 + lo) * 64 + (((kc*4 + hi) ^ lsw) * 8));
                #pragma unroll
                for (int qs = 0; qs < 2; ++qs)
                    s[qs][ms] = mfma16(kf, aq[qs][kc], s[qs][ms]);
            }
        }
        bf16x8 vf[4];
        #pragma unroll
        for (int ds = 0; ds < 4; ++ds)
            vf[ds] = ld_bf8(vt + (ds*16 + lo) * 64 + (((kh*4 + hi) ^ lsw) * 8));
        #pragma unroll
        for (int qs = 0; qs < 2; ++qs) {
            float p[2][4];
            #pragma unroll
            for (int ms = 0; ms < 2; ++ms)
                #pragma unroll
                for (int r = 0; r < 4; ++r)
                    p[ms][r] = __expf(s[qs][ms][r]);
            l_p[qs] += ((p[0][0] + p[0][1]) + (p[0][2] + p[0][3]))
                     + ((p[1][0] + p[1][1]) + (p[1][2] + p[1][3]));
            uint4_t w;
            w[0] = pack2(p[0][0], p[0][1]);
            w[1] = pack2(p[0][2], p[0][3]);
            w[2] = pack2(p[1][0], p[1][1]);
            w[3] = pack2(p[1][2], p[1][3]);
            bf16x8 apf = __builtin_bit_cast(bf16x8, w);
            #pragma unroll
            for (int ds = 0; ds < 4; ++ds)
                acc[qs][ds] = mfma16(apf, vf[ds], acc[qs][ds]);
        }
    };

    constexpr int NIT = Nd / 128;     // 32 iterations of 128 keys
    gload(0);
    dswrite(0);
    __syncthreads();
    for (int it = 0; it < NIT; ++it) {
        const int cur = it & 1;
        if (it + 1 < NIT) gload(it + 1);
        __builtin_amdgcn_sched_barrier(0);       // pin loads (validated)
        compute(cur);
        if (it + 1 < NIT) dswrite(cur ^ 1);
        __syncthreads();                         // one barrier per 128 keys
    }

    // ---- epilogue: reduce over (kh,tp) groups via overlay on dead tiles ----
    float lh[2];
    #pragma unroll
    for (int qs = 0; qs < 2; ++qs) {
        float ps = l_p[qs];
        ps += __shfl_xor(ps, 16, 64);
        ps += __shfl_xor(ps, 32, 64);            // all lanes: partial l for q = qbase + lo
        lh[qs] = ps;
    }
    float* red = (float*)&kv_lds[0][0][0][0];    // 3 groups x 16 KB = 48 KB overlay
    const int g = (kh * 2 + tp) - 1;             // -1 for the combining wave
    if (g >= 0) {
        #pragma unroll
        for (int qs = 0; qs < 2; ++qs) {
            #pragma unroll
            for (int ds = 0; ds < 4; ++ds) {
                const int idx = ((g * 2 + qh) * 2 + qs) * 4 + ds;
                *(f32x4*)&red[idx * 256 + l * 4] = acc[qs][ds];
            }
            red_l[g][qh][qs][lo] = lh[qs];
        }
    }
    __syncthreads();
    if (g < 0) {
        #pragma unroll
        for (int qs = 0; qs < 2; ++qs) {
            #pragma unroll
            for (int gg = 0; gg < 3; ++gg) {
                #pragma unroll
                for (int ds = 0; ds < 4; ++ds) {
                    const int idx = ((gg * 2 + qh) * 2 + qs) * 4 + ds;
                    acc[qs][ds] += *(const f32x4*)&red[idx * 256 + l * 4];
                }
                lh[qs] += red_l[gg][qh][qs][lo];
            }
            #pragma unroll
            for (int r = 0; r < 4; ++r) {
                float lq = __shfl(lh[qs], hi * 4 + r, 16);
                float rl = 1.0f / lq;
                #pragma unroll
                for (int ds = 0; ds < 4; ++ds) {
                    float o = acc[qs][ds][r] * rl;
                    o_nd[((size_t)b * Nd + n0 + qh*32 + qs*16 + hi*4 + r) * 64 + ds*16 + lo] = f2bf(o);
                }
            }
        }
    }
}

// ---------------- K3: output projection + residual ----------------
__global__ __launch_bounds__(256) void k_oproj(
    const unsigned short* __restrict__ o_nd,
    const unsigned short* __restrict__ wo,
    const float* __restrict__ bo,
    const float* __restrict__ gamma,
    const float* __restrict__ x,
    float* __restrict__ out)
{
    const int b   = blockIdx.y;
    const int n0  = blockIdx.x * 64;
    const int tid = threadIdx.x, wid = tid >> 6, l = tid & 63;
    const int lo  = l & 15, hi = l >> 4;
    const int n0w = n0 + wid * 16;
    const float g = gamma[0];

    bf16x8 ao[2];
    #pragma unroll
    for (int kc = 0; kc < 2; ++kc)
        ao[kc] = ld_bf8(o_nd + ((size_t)b * Nd + n0w + lo) * 64 + kc*32 + hi*8);

    for (int ct = 0; ct < 32; ++ct) {
        f32x4 acc = {};
        #pragma unroll
        for (int kc = 0; kc < 2; ++kc) {
            bf16x8 bw = ld_bf8(wo + (ct*16 + lo) * 64 + kc*32 + hi*8);
            acc = mfma16(ao[kc], bw, acc);
        }
        const int c = ct*16 + lo;
        const float bc = bo[c];
        const size_t base = ((size_t)b * Cd + c) * Nd + n0w + hi*4;
        float4_t xv = *(const float4_t*)(x + base);
        float4_t ov;
        #pragma unroll
        for (int r = 0; r < 4; ++r) ov[r] = g * (acc[r] + bc) + xv[r];
        *(float4_t*)(out + base) = ov;
    }
}

extern "C" void kernel_launch(void* const* d_in, const int* in_sizes, int n_in,
                              void* d_out, int out_size, void* d_ws, size_t ws_size,
                              hipStream_t stream) {
    (void)in_sizes; (void)n_in; (void)out_size; (void)ws_size;
    const float* x  = (const float*)d_in[0];
    const float* Wq = (const float*)d_in[1];
    const float* bq = (const float*)d_in[2];
    const float* Wk = (const float*)d_in[3];
    const float* bk = (const float*)d_in[4];
    const float* Wv = (const float*)d_in[5];
    const float* bv = (const float*)d_in[6];
    const float* Wo = (const float*)d_in[7];
    const float* bo = (const float*)d_in[8];
    const float* gm = (const float*)d_in[9];
    float* out = (float*)d_out;

    unsigned short* w4   = (unsigned short*)d_ws;          // 4 x 32768 bf16 weights
    unsigned short* q_nd = w4 + 131072;
    unsigned short* k_nd = q_nd + (size_t)Bd * Nd * Dd;
    unsigned short* v_dn = k_nd + (size_t)Bd * Nd * Dd;
    unsigned short* o_nd = v_dn + (size_t)Bd * Nd * Dd;

    k_cvtw<<<128, 256, 0, stream>>>(Wq, Wk, Wv, Wo, w4);
    dim3 gq(Nd / 32, Bd);
    k_qkv<<<gq, 128, 0, stream>>>(x, w4, w4 + 32768, w4 + 65536, bq, bk, bv, q_nd, k_nd, v_dn);
    k_attn<<<512, 512, 0, stream>>>(q_nd, k_nd, v_dn, o_nd);
    dim3 g1(Nd / 64, Bd);
    k_oproj<<<g1, 256, 0, stream>>>(o_nd, w4 + 98304, bo, gm, x, out);
}